// Round 6
// baseline (229.786 us; speedup 1.0000x reference)
//
#include <hip/hip_runtime.h>

#define D 128
#define GROWS 32
#define HCHUNKS 64   // edge chunks
#define RNG_H 8064   // nodes/range in hist (float+int LDS = 63 KB)
#define RNG_S 16128  // nodes/range in scatter (int LDS = 63 KB)

// ---------------------------------------------------------------------------
// GCN: out = A_norm @ (x @ W^T) + b.
// R1: per-edge f32 atomics write through HBM (300MB) -> CSR gather.
// R2: 2-atomics/edge build = 37MB atomic sectors ~58us.
// R3: fusing GEMM with atomic pass didn't overlap (throughput-bound).
// R4: bucket LDS-tile agg regressed 537us (serial shfl inner loop).
// R5: 1-atomic rank pass + LDS-histogram degree + bf16 y (abs 0.016, 5x
//     margin). All kernels <40us; harness ws-poison fills are top dispatches.
// R6: fully atomic-free CSR build: chunked LDS histograms (deg+cnt), per-chunk
//     base cursors from prefix arithmetic, scatter bumps LDS cursors.
// ---------------------------------------------------------------------------

__device__ __forceinline__ unsigned bf16rne(float f) {
  unsigned u = __float_as_uint(f);
  return (u + 0x7FFFu + ((u >> 16) & 1u)) >> 16;
}

__device__ __forceinline__ float4 bf16x4(uint2 u) {
  float4 r;
  r.x = __uint_as_float(u.x << 16);
  r.y = __uint_as_float(u.x & 0xFFFF0000u);
  r.z = __uint_as_float(u.y << 16);
  r.w = __uint_as_float(u.y & 0xFFFF0000u);
  return r;
}

__global__ __launch_bounds__(256) void k_setup(const float* __restrict__ W,
                                               const int* __restrict__ ei,
                                               float* __restrict__ Wt,
                                               int* __restrict__ flag) {
  int i = blockIdx.x * 256 + threadIdx.x;
  if (i < D * D) {
    int c = i >> 7, k = i & 127;
    Wt[k * D + c] = W[i];  // transpose for coalesced GEMM reads
  }
  if (i == 0) {
    // int64-vs-int32 edge_index layout: ids < 2^31 so int64(LE) odd dwords==0
    flag[0] = (ei[1] == 0 && ei[3] == 0 && ei[5] == 0 && ei[7] == 0) ? 1 : 0;
  }
}

// y = x @ W^T, stored bf16 (halves gather traffic; abs err ~0.004)
__global__ __launch_bounds__(256) void k_gemm(const float* __restrict__ x,
                                              const float* __restrict__ Wt,
                                              uint2* __restrict__ yb,
                                              int N) {
  __shared__ float Xs[GROWS * D];
  const int tid = threadIdx.x;
  const int row0 = blockIdx.x * GROWS;

  for (int f = tid; f < GROWS * D / 4; f += 256) {
    int r = row0 + ((f * 4) >> 7);
    float4 v = make_float4(0.f, 0.f, 0.f, 0.f);
    if (r < N)
      v = reinterpret_cast<const float4*>(x)[(size_t)row0 * (D / 4) + f];
    reinterpret_cast<float4*>(Xs)[f] = v;
  }
  __syncthreads();

  const int c0 = (tid & 31) * 4;
  const int r0 = (tid >> 5) * 4;
  float acc[4][4];
#pragma unroll
  for (int i = 0; i < 4; ++i)
#pragma unroll
    for (int j = 0; j < 4; ++j) acc[i][j] = 0.f;

#pragma unroll 4
  for (int k = 0; k < D; ++k) {
    float4 wv = reinterpret_cast<const float4*>(Wt)[(k * D + c0) >> 2];
    float xr[4];
#pragma unroll
    for (int i = 0; i < 4; ++i) xr[i] = Xs[(r0 + i) * D + k];
#pragma unroll
    for (int i = 0; i < 4; ++i) {
      acc[i][0] += xr[i] * wv.x;
      acc[i][1] += xr[i] * wv.y;
      acc[i][2] += xr[i] * wv.z;
      acc[i][3] += xr[i] * wv.w;
    }
  }
#pragma unroll
  for (int i = 0; i < 4; ++i) {
    int row = row0 + r0 + i;
    if (row < N) {
      uint2 u;
      u.x = bf16rne(acc[i][0]) | (bf16rne(acc[i][1]) << 16);
      u.y = bf16rne(acc[i][2]) | (bf16rne(acc[i][3]) << 16);
      yb[(size_t)row * 32 + (tid & 31)] = u;
    }
  }
}

// chunked private histograms: deg (float over src) + cnt (int over tgt).
// grid (HCHUNKS, nrangesH). No global atomics.
__global__ __launch_bounds__(256) void k_hist(const int* __restrict__ ei,
                                              const float* __restrict__ ew,
                                              float* __restrict__ pdeg,
                                              int* __restrict__ pcnt,
                                              const int* __restrict__ flag,
                                              int E) {
  __shared__ float hd[RNG_H];
  __shared__ int hc[RNG_H];
  const int tid = threadIdx.x;
  const int chunk = blockIdx.x, r = blockIdx.y;
  const int lo = r * RNG_H;
  for (int i = tid; i < RNG_H; i += 256) { hd[i] = 0.f; hc[i] = 0; }
  __syncthreads();

  const int epc = (E + HCHUNKS - 1) / HCHUNKS;
  const int e0 = chunk * epc;
  const int e1 = min(e0 + epc, E);
  const bool f64 = flag[0] != 0;
  const int2* ei2 = reinterpret_cast<const int2*>(ei);
  for (int e = e0 + tid; e < e1; e += 256) {
    int s = f64 ? ei2[e].x : ei[e];
    int t = f64 ? ei2[E + e].x : ei[E + e];
    int ds = s - lo;
    if ((unsigned)ds < (unsigned)RNG_H) atomicAdd(&hd[ds], ew[e]);
    int dt = t - lo;
    if ((unsigned)dt < (unsigned)RNG_H) atomicAdd(&hc[dt], 1);
  }
  __syncthreads();
  size_t base = ((size_t)r * HCHUNKS + chunk) * RNG_H;
  for (int i = tid; i < RNG_H; i += 256) {
    pdeg[base + i] = hd[i];
    pcnt[base + i] = hc[i];
  }
}

__device__ __forceinline__ int wave_incl_scan(int v, int lane) {
#pragma unroll
  for (int o = 1; o < 64; o <<= 1) {
    int t = __shfl_up(v, o);
    if (lane >= o) v += t;
  }
  return v;
}

// fused: reduce pdeg -> dinv, reduce pcnt -> v, block-exclusive-scan v
__global__ __launch_bounds__(256) void k_scan1(const float* __restrict__ pdeg,
                                               const int* __restrict__ pcnt,
                                               float* __restrict__ dinv,
                                               int* __restrict__ rowptr,
                                               int* __restrict__ blocksum,
                                               int N) {
  __shared__ int wtot[4];
  int tid = threadIdx.x;
  int i = blockIdx.x * 256 + tid;
  int v = 0;
  if (i < N) {
    int r = i / RNG_H, off = i - r * RNG_H;
    size_t base = (size_t)r * HCHUNKS * RNG_H + off;
    float s = 0.f;
    int c = 0;
#pragma unroll 8
    for (int k = 0; k < HCHUNKS; ++k) {
      s += pdeg[base + (size_t)k * RNG_H];
      c += pcnt[base + (size_t)k * RNG_H];
    }
    dinv[i] = rsqrtf(s + 1.0f);  // +1 = self-loop weight
    v = c;
  }
  int lane = tid & 63, wv = tid >> 6;
  int inc = wave_incl_scan(v, lane);
  if (lane == 63) wtot[wv] = inc;
  __syncthreads();
  if (tid == 0) {
    int r = 0;
#pragma unroll
    for (int k = 0; k < 4; ++k) { int t = wtot[k]; wtot[k] = r; r += t; }
  }
  __syncthreads();
  int exc = wtot[wv] + inc - v;
  if (i < N) rowptr[i] = exc;
  if (tid == 255) blocksum[blockIdx.x] = wtot[3] + inc;
}

__global__ __launch_bounds__(64) void k_scan2(int* __restrict__ blocksum,
                                              int* __restrict__ blockoff,
                                              int nb) {
  int lane = threadIdx.x;
  int carry = 0;
  for (int base = 0; base < nb; base += 64) {
    int idx = base + lane;
    int v = (idx < nb) ? blocksum[idx] : 0;
    int inc = wave_incl_scan(v, lane);
    if (idx < nb) blockoff[idx] = carry + inc - v;
    carry += __shfl(inc, 63);
  }
}

// finalize rowptr; emit per-chunk cursors base[c*N+v] = rowptr[v]+prefix(cnt)
__global__ __launch_bounds__(256) void k_scan3base(int* __restrict__ rowptr,
                                                   const int* __restrict__ blockoff,
                                                   const int* __restrict__ pcnt,
                                                   int* __restrict__ cbase,
                                                   int N, int E) {
  int i = blockIdx.x * 256 + threadIdx.x;
  if (i >= N) {
    if (i == N) rowptr[N] = E;
    return;
  }
  int rp = rowptr[i] + blockoff[blockIdx.x];
  rowptr[i] = rp;
  if (i == 0) rowptr[N] = E;  // in case N % 256 == 0 edge
  int r = i / RNG_H, off = i - r * RNG_H;
  size_t pb = (size_t)r * HCHUNKS * RNG_H + off;
  int run = rp;
#pragma unroll 8
  for (int c = 0; c < HCHUNKS; ++c) {
    cbase[(size_t)c * N + i] = run;
    run += pcnt[pb + (size_t)c * RNG_H];
  }
}

// scatter: LDS cursor bump gives final CSR slot; plain 8B stores.
// grid (HCHUNKS, nrangesS).
__global__ __launch_bounds__(256) void k_scatter(const int* __restrict__ ei,
                                                 const float* __restrict__ ew,
                                                 const float* __restrict__ dinv,
                                                 const int* __restrict__ cbase,
                                                 int2* __restrict__ edges,
                                                 const int* __restrict__ flag,
                                                 int N, int E) {
  __shared__ int hb[RNG_S];
  const int tid = threadIdx.x;
  const int chunk = blockIdx.x, r = blockIdx.y;
  const int lo = r * RNG_S;
  for (int j = tid; j < RNG_S; j += 256) {
    int v = lo + j;
    hb[j] = (v < N) ? cbase[(size_t)chunk * N + v] : 0;
  }
  __syncthreads();

  const int epc = (E + HCHUNKS - 1) / HCHUNKS;
  const int e0 = chunk * epc;
  const int e1 = min(e0 + epc, E);
  const bool f64 = flag[0] != 0;
  const int2* ei2 = reinterpret_cast<const int2*>(ei);
  for (int e = e0 + tid; e < e1; e += 256) {
    int t = f64 ? ei2[E + e].x : ei[E + e];
    int dt = t - lo;
    if ((unsigned)dt < (unsigned)RNG_S) {
      int s = f64 ? ei2[e].x : ei[e];
      int pos = atomicAdd(&hb[dt], 1);  // LDS atomic -> final global slot
      edges[pos] = make_int2(s, __float_as_int(ew[e] * dinv[s]));
    }
  }
}

// gather: node per wave; 32-lane halves, 4 bf16/lane, 8 rows in flight.
// out = b + dt*(sum_e wn*y[s] + dt*y[node])
__global__ __launch_bounds__(256) void k_gather(const int* __restrict__ rowptr,
                                                const int2* __restrict__ edges,
                                                const uint2* __restrict__ yb,
                                                const float* __restrict__ dinv,
                                                const float* __restrict__ b,
                                                float* __restrict__ out,
                                                int N) {
  const int tid = threadIdx.x;
  const int node = blockIdx.x * 4 + (tid >> 6);
  if (node >= N) return;
  const int lane = tid & 63, half = lane >> 5, l32 = lane & 31;

  const float dt = dinv[node];
  const float4 yself = bf16x4(yb[(size_t)node * 32 + l32]);
  const float4 bb = reinterpret_cast<const float4*>(b)[l32];

  float4 acc = make_float4(0.f, 0.f, 0.f, 0.f);
  const int end = rowptr[node + 1];
  int e = rowptr[node] + half;
  for (; e + 6 < end; e += 8) {  // 4 rows in flight per half
    int2 e0 = edges[e], e1 = edges[e + 2], e2 = edges[e + 4], e3 = edges[e + 6];
    float4 v0 = bf16x4(yb[(size_t)e0.x * 32 + l32]);
    float4 v1 = bf16x4(yb[(size_t)e1.x * 32 + l32]);
    float4 v2 = bf16x4(yb[(size_t)e2.x * 32 + l32]);
    float4 v3 = bf16x4(yb[(size_t)e3.x * 32 + l32]);
    float w0 = __int_as_float(e0.y), w1 = __int_as_float(e1.y);
    float w2 = __int_as_float(e2.y), w3 = __int_as_float(e3.y);
    acc.x += w0 * v0.x; acc.y += w0 * v0.y; acc.z += w0 * v0.z; acc.w += w0 * v0.w;
    acc.x += w1 * v1.x; acc.y += w1 * v1.y; acc.z += w1 * v1.z; acc.w += w1 * v1.w;
    acc.x += w2 * v2.x; acc.y += w2 * v2.y; acc.z += w2 * v2.z; acc.w += w2 * v2.w;
    acc.x += w3 * v3.x; acc.y += w3 * v3.y; acc.z += w3 * v3.z; acc.w += w3 * v3.w;
  }
  for (; e < end; e += 2) {
    int2 e0 = edges[e];
    float4 v0 = bf16x4(yb[(size_t)e0.x * 32 + l32]);
    float w0 = __int_as_float(e0.y);
    acc.x += w0 * v0.x; acc.y += w0 * v0.y; acc.z += w0 * v0.z; acc.w += w0 * v0.w;
  }
  acc.x += __shfl(acc.x, l32 + 32);
  acc.y += __shfl(acc.y, l32 + 32);
  acc.z += __shfl(acc.z, l32 + 32);
  acc.w += __shfl(acc.w, l32 + 32);
  if (half == 0) {
    float4 r;
    r.x = bb.x + dt * (acc.x + dt * yself.x);
    r.y = bb.y + dt * (acc.y + dt * yself.y);
    r.z = bb.z + dt * (acc.z + dt * yself.z);
    r.w = bb.w + dt * (acc.w + dt * yself.w);
    reinterpret_cast<float4*>(out)[(size_t)node * 32 + l32] = r;
  }
}

extern "C" void kernel_launch(void* const* d_in, const int* in_sizes, int n_in,
                              void* d_out, int out_size, void* d_ws, size_t ws_size,
                              hipStream_t stream) {
  const float* x = (const float*)d_in[0];
  const int* ei = (const int*)d_in[1];
  const float* ew = (const float*)d_in[2];
  const float* W = (const float*)d_in[3];
  const float* b = (const float*)d_in[4];
  float* out = (float*)d_out;

  const int N = in_sizes[0] / D;
  const int E = in_sizes[2];
  const int NB = (N + 255) / 256;
  const int nrH = (N + RNG_H - 1) / RNG_H;
  const int nrS = (N + RNG_S - 1) / RNG_S;

  char* ws = (char*)d_ws;
  size_t off = 0;
  auto alloc = [&](size_t bytes) {
    char* p = ws + off;
    off = (off + bytes + 255) & ~(size_t)255;
    return p;
  };
  float* Wt = (float*)alloc((size_t)D * D * 4);
  uint2* yb = (uint2*)alloc((size_t)N * D * 2);  // bf16 y
  float* dinv = (float*)alloc((size_t)N * 4);
  float* pdeg = (float*)alloc((size_t)nrH * HCHUNKS * RNG_H * 4);
  int* pcnt = (int*)alloc((size_t)nrH * HCHUNKS * RNG_H * 4);
  int* cbase = (int*)alloc((size_t)HCHUNKS * N * 4);
  int* rowptr = (int*)alloc((size_t)(N + 1) * 4);
  int* blocksum = (int*)alloc((size_t)NB * 4);
  int* blockoff = (int*)alloc((size_t)NB * 4);
  int2* edges = (int2*)alloc((size_t)E * 8);
  int* flag = (int*)alloc(4);

  hipLaunchKernelGGL(k_setup, dim3((D * D + 255) / 256), dim3(256), 0, stream,
                     W, ei, Wt, flag);
  hipLaunchKernelGGL(k_gemm, dim3((N + GROWS - 1) / GROWS), dim3(256), 0,
                     stream, x, Wt, yb, N);
  hipLaunchKernelGGL(k_hist, dim3(HCHUNKS, nrH), dim3(256), 0, stream,
                     ei, ew, pdeg, pcnt, flag, E);
  hipLaunchKernelGGL(k_scan1, dim3(NB), dim3(256), 0, stream,
                     pdeg, pcnt, dinv, rowptr, blocksum, N);
  hipLaunchKernelGGL(k_scan2, dim3(1), dim3(64), 0, stream,
                     blocksum, blockoff, NB);
  hipLaunchKernelGGL(k_scan3base, dim3(NB), dim3(256), 0, stream,
                     rowptr, blockoff, pcnt, cbase, N, E);
  hipLaunchKernelGGL(k_scatter, dim3(HCHUNKS, nrS), dim3(256), 0, stream,
                     ei, ew, dinv, cbase, edges, flag, N, E);
  hipLaunchKernelGGL(k_gather, dim3((N + 3) / 4), dim3(256), 0, stream,
                     rowptr, edges, yb, dinv, b, out, N);
}

// Round 7
// 223.015 us; speedup vs baseline: 1.0304x; 1.0304x over previous
//
#include <hip/hip_runtime.h>

#define D 128
#define GROWS 32
#define HCHUNKS 128  // edge chunks (epc = 4688 < 2^16 -> u16 counts)
#define RNG 8064     // nodes per range: hist LDS f32+i32 = 63KB, scatter 32KB

// ---------------------------------------------------------------------------
// GCN: out = A_norm @ (x @ W^T) + b.
// R1: per-edge f32 atomics write through HBM (300MB) -> CSR gather.
// R2: 2-atomics/edge build = 37MB atomic sectors ~58us.
// R3: fusing GEMM with atomic pass didn't overlap (throughput-bound).
// R4: bucket LDS-tile agg regressed 537us (serial shfl inner loop).
// R5: 1-atomic rank + LDS-hist degree + bf16 y. 228us.
// R6: atomic-free build, but scatter = 44.6us @ 8% occupancy (63KB LDS,
//     256 blocks, 4x redundant reads). 229us.
// R7: scatter/hist at HCHUNKS=128, scatter RNG=8064 (32KB LDS -> ~4 blk/CU,
//     896 blocks); pcnt u16. Expect scatter ~15us, total ~190us.
// ---------------------------------------------------------------------------

__device__ __forceinline__ unsigned bf16rne(float f) {
  unsigned u = __float_as_uint(f);
  return (u + 0x7FFFu + ((u >> 16) & 1u)) >> 16;
}

__device__ __forceinline__ float4 bf16x4(uint2 u) {
  float4 r;
  r.x = __uint_as_float(u.x << 16);
  r.y = __uint_as_float(u.x & 0xFFFF0000u);
  r.z = __uint_as_float(u.y << 16);
  r.w = __uint_as_float(u.y & 0xFFFF0000u);
  return r;
}

__global__ __launch_bounds__(256) void k_setup(const float* __restrict__ W,
                                               const int* __restrict__ ei,
                                               float* __restrict__ Wt,
                                               int* __restrict__ flag) {
  int i = blockIdx.x * 256 + threadIdx.x;
  if (i < D * D) {
    int c = i >> 7, k = i & 127;
    Wt[k * D + c] = W[i];  // transpose for coalesced GEMM reads
  }
  if (i == 0) {
    // int64-vs-int32 edge_index layout: ids < 2^31 so int64(LE) odd dwords==0
    flag[0] = (ei[1] == 0 && ei[3] == 0 && ei[5] == 0 && ei[7] == 0) ? 1 : 0;
  }
}

// y = x @ W^T, stored bf16 (halves gather traffic; abs err ~0.004)
__global__ __launch_bounds__(256) void k_gemm(const float* __restrict__ x,
                                              const float* __restrict__ Wt,
                                              uint2* __restrict__ yb,
                                              int N) {
  __shared__ float Xs[GROWS * D];
  const int tid = threadIdx.x;
  const int row0 = blockIdx.x * GROWS;

  for (int f = tid; f < GROWS * D / 4; f += 256) {
    int r = row0 + ((f * 4) >> 7);
    float4 v = make_float4(0.f, 0.f, 0.f, 0.f);
    if (r < N)
      v = reinterpret_cast<const float4*>(x)[(size_t)row0 * (D / 4) + f];
    reinterpret_cast<float4*>(Xs)[f] = v;
  }
  __syncthreads();

  const int c0 = (tid & 31) * 4;
  const int r0 = (tid >> 5) * 4;
  float acc[4][4];
#pragma unroll
  for (int i = 0; i < 4; ++i)
#pragma unroll
    for (int j = 0; j < 4; ++j) acc[i][j] = 0.f;

#pragma unroll 4
  for (int k = 0; k < D; ++k) {
    float4 wv = reinterpret_cast<const float4*>(Wt)[(k * D + c0) >> 2];
    float xr[4];
#pragma unroll
    for (int i = 0; i < 4; ++i) xr[i] = Xs[(r0 + i) * D + k];
#pragma unroll
    for (int i = 0; i < 4; ++i) {
      acc[i][0] += xr[i] * wv.x;
      acc[i][1] += xr[i] * wv.y;
      acc[i][2] += xr[i] * wv.z;
      acc[i][3] += xr[i] * wv.w;
    }
  }
#pragma unroll
  for (int i = 0; i < 4; ++i) {
    int row = row0 + r0 + i;
    if (row < N) {
      uint2 u;
      u.x = bf16rne(acc[i][0]) | (bf16rne(acc[i][1]) << 16);
      u.y = bf16rne(acc[i][2]) | (bf16rne(acc[i][3]) << 16);
      yb[(size_t)row * 32 + (tid & 31)] = u;
    }
  }
}

// chunked private histograms: deg (f32 over src) + cnt (i32 over tgt, stored
// u16). grid (HCHUNKS, nranges). No global atomics.
__global__ __launch_bounds__(256) void k_hist(const int* __restrict__ ei,
                                              const float* __restrict__ ew,
                                              float* __restrict__ pdeg,
                                              unsigned short* __restrict__ pcnt,
                                              const int* __restrict__ flag,
                                              int E) {
  __shared__ float hd[RNG];
  __shared__ int hc[RNG];
  const int tid = threadIdx.x;
  const int chunk = blockIdx.x, r = blockIdx.y;
  const int lo = r * RNG;
  for (int i = tid; i < RNG; i += 256) { hd[i] = 0.f; hc[i] = 0; }
  __syncthreads();

  const int epc = (E + HCHUNKS - 1) / HCHUNKS;
  const int e0 = chunk * epc;
  const int e1 = min(e0 + epc, E);
  const bool f64 = flag[0] != 0;
  const int2* ei2 = reinterpret_cast<const int2*>(ei);
  for (int e = e0 + tid; e < e1; e += 256) {
    int s = f64 ? ei2[e].x : ei[e];
    int t = f64 ? ei2[E + e].x : ei[E + e];
    int ds = s - lo;
    if ((unsigned)ds < (unsigned)RNG) atomicAdd(&hd[ds], ew[e]);
    int dt = t - lo;
    if ((unsigned)dt < (unsigned)RNG) atomicAdd(&hc[dt], 1);
  }
  __syncthreads();
  size_t base = ((size_t)r * HCHUNKS + chunk) * RNG;
  for (int i = tid; i < RNG; i += 256) {
    pdeg[base + i] = hd[i];
    pcnt[base + i] = (unsigned short)hc[i];
  }
}

__device__ __forceinline__ int wave_incl_scan(int v, int lane) {
#pragma unroll
  for (int o = 1; o < 64; o <<= 1) {
    int t = __shfl_up(v, o);
    if (lane >= o) v += t;
  }
  return v;
}

// fused: reduce pdeg -> dinv, reduce pcnt -> v, block-exclusive-scan v
__global__ __launch_bounds__(256) void k_scan1(const float* __restrict__ pdeg,
                                               const unsigned short* __restrict__ pcnt,
                                               float* __restrict__ dinv,
                                               int* __restrict__ rowptr,
                                               int* __restrict__ blocksum,
                                               int N) {
  __shared__ int wtot[4];
  int tid = threadIdx.x;
  int i = blockIdx.x * 256 + tid;
  int v = 0;
  if (i < N) {
    int r = i / RNG, off = i - r * RNG;
    size_t base = (size_t)r * HCHUNKS * RNG + off;
    float s = 0.f;
    int c = 0;
#pragma unroll 8
    for (int k = 0; k < HCHUNKS; ++k) {
      s += pdeg[base + (size_t)k * RNG];
      c += pcnt[base + (size_t)k * RNG];
    }
    dinv[i] = rsqrtf(s + 1.0f);  // +1 = self-loop weight
    v = c;
  }
  int lane = tid & 63, wv = tid >> 6;
  int inc = wave_incl_scan(v, lane);
  if (lane == 63) wtot[wv] = inc;
  __syncthreads();
  if (tid == 0) {
    int r = 0;
#pragma unroll
    for (int k = 0; k < 4; ++k) { int t = wtot[k]; wtot[k] = r; r += t; }
  }
  __syncthreads();
  int exc = wtot[wv] + inc - v;
  if (i < N) rowptr[i] = exc;
  if (tid == 255) blocksum[blockIdx.x] = wtot[3] + inc;
}

__global__ __launch_bounds__(64) void k_scan2(int* __restrict__ blocksum,
                                              int* __restrict__ blockoff,
                                              int nb) {
  int lane = threadIdx.x;
  int carry = 0;
  for (int base = 0; base < nb; base += 64) {
    int idx = base + lane;
    int v = (idx < nb) ? blocksum[idx] : 0;
    int inc = wave_incl_scan(v, lane);
    if (idx < nb) blockoff[idx] = carry + inc - v;
    carry += __shfl(inc, 63);
  }
}

// finalize rowptr; emit per-chunk cursors cbase[c*N+v] = rowptr[v]+prefix(cnt)
__global__ __launch_bounds__(256) void k_scan3base(int* __restrict__ rowptr,
                                                   const int* __restrict__ blockoff,
                                                   const unsigned short* __restrict__ pcnt,
                                                   int* __restrict__ cbase,
                                                   int N, int E) {
  int i = blockIdx.x * 256 + threadIdx.x;
  if (i >= N) {
    if (i == N) rowptr[N] = E;
    return;
  }
  int rp = rowptr[i] + blockoff[blockIdx.x];
  rowptr[i] = rp;
  int r = i / RNG, off = i - r * RNG;
  size_t pb = (size_t)r * HCHUNKS * RNG + off;
  int run = rp;
#pragma unroll 8
  for (int c = 0; c < HCHUNKS; ++c) {
    cbase[(size_t)c * N + i] = run;
    run += pcnt[pb + (size_t)c * RNG];
  }
}

// scatter: LDS cursor bump gives final CSR slot; plain 8B stores.
// grid (HCHUNKS, nranges); 32KB LDS -> ~4 blocks/CU.
__global__ __launch_bounds__(256) void k_scatter(const int* __restrict__ ei,
                                                 const float* __restrict__ ew,
                                                 const float* __restrict__ dinv,
                                                 const int* __restrict__ cbase,
                                                 int2* __restrict__ edges,
                                                 const int* __restrict__ flag,
                                                 int N, int E) {
  __shared__ int hb[RNG];
  const int tid = threadIdx.x;
  const int chunk = blockIdx.x, r = blockIdx.y;
  const int lo = r * RNG;
  for (int j = tid; j < RNG; j += 256) {
    int v = lo + j;
    hb[j] = (v < N) ? cbase[(size_t)chunk * N + v] : 0;
  }
  __syncthreads();

  const int epc = (E + HCHUNKS - 1) / HCHUNKS;
  const int e0 = chunk * epc;
  const int e1 = min(e0 + epc, E);
  const bool f64 = flag[0] != 0;
  const int2* ei2 = reinterpret_cast<const int2*>(ei);
  for (int e = e0 + tid; e < e1; e += 256) {
    int t = f64 ? ei2[E + e].x : ei[E + e];
    int dt = t - lo;
    if ((unsigned)dt < (unsigned)RNG) {
      int s = f64 ? ei2[e].x : ei[e];
      int pos = atomicAdd(&hb[dt], 1);  // LDS atomic -> final global slot
      edges[pos] = make_int2(s, __float_as_int(ew[e] * dinv[s]));
    }
  }
}

// gather: node per wave; 32-lane halves, 4 bf16/lane, 8 rows in flight.
// out = b + dt*(sum_e wn*y[s] + dt*y[node])
__global__ __launch_bounds__(256) void k_gather(const int* __restrict__ rowptr,
                                                const int2* __restrict__ edges,
                                                const uint2* __restrict__ yb,
                                                const float* __restrict__ dinv,
                                                const float* __restrict__ b,
                                                float* __restrict__ out,
                                                int N) {
  const int tid = threadIdx.x;
  const int node = blockIdx.x * 4 + (tid >> 6);
  if (node >= N) return;
  const int lane = tid & 63, half = lane >> 5, l32 = lane & 31;

  const float dt = dinv[node];
  const float4 yself = bf16x4(yb[(size_t)node * 32 + l32]);
  const float4 bb = reinterpret_cast<const float4*>(b)[l32];

  float4 acc = make_float4(0.f, 0.f, 0.f, 0.f);
  const int end = rowptr[node + 1];
  int e = rowptr[node] + half;
  for (; e + 6 < end; e += 8) {  // 4 rows in flight per half
    int2 e0 = edges[e], e1 = edges[e + 2], e2 = edges[e + 4], e3 = edges[e + 6];
    float4 v0 = bf16x4(yb[(size_t)e0.x * 32 + l32]);
    float4 v1 = bf16x4(yb[(size_t)e1.x * 32 + l32]);
    float4 v2 = bf16x4(yb[(size_t)e2.x * 32 + l32]);
    float4 v3 = bf16x4(yb[(size_t)e3.x * 32 + l32]);
    float w0 = __int_as_float(e0.y), w1 = __int_as_float(e1.y);
    float w2 = __int_as_float(e2.y), w3 = __int_as_float(e3.y);
    acc.x += w0 * v0.x; acc.y += w0 * v0.y; acc.z += w0 * v0.z; acc.w += w0 * v0.w;
    acc.x += w1 * v1.x; acc.y += w1 * v1.y; acc.z += w1 * v1.z; acc.w += w1 * v1.w;
    acc.x += w2 * v2.x; acc.y += w2 * v2.y; acc.z += w2 * v2.z; acc.w += w2 * v2.w;
    acc.x += w3 * v3.x; acc.y += w3 * v3.y; acc.z += w3 * v3.z; acc.w += w3 * v3.w;
  }
  for (; e < end; e += 2) {
    int2 e0 = edges[e];
    float4 v0 = bf16x4(yb[(size_t)e0.x * 32 + l32]);
    float w0 = __int_as_float(e0.y);
    acc.x += w0 * v0.x; acc.y += w0 * v0.y; acc.z += w0 * v0.z; acc.w += w0 * v0.w;
  }
  acc.x += __shfl(acc.x, l32 + 32);
  acc.y += __shfl(acc.y, l32 + 32);
  acc.z += __shfl(acc.z, l32 + 32);
  acc.w += __shfl(acc.w, l32 + 32);
  if (half == 0) {
    float4 r;
    r.x = bb.x + dt * (acc.x + dt * yself.x);
    r.y = bb.y + dt * (acc.y + dt * yself.y);
    r.z = bb.z + dt * (acc.z + dt * yself.z);
    r.w = bb.w + dt * (acc.w + dt * yself.w);
    reinterpret_cast<float4*>(out)[(size_t)node * 32 + l32] = r;
  }
}

extern "C" void kernel_launch(void* const* d_in, const int* in_sizes, int n_in,
                              void* d_out, int out_size, void* d_ws, size_t ws_size,
                              hipStream_t stream) {
  const float* x = (const float*)d_in[0];
  const int* ei = (const int*)d_in[1];
  const float* ew = (const float*)d_in[2];
  const float* W = (const float*)d_in[3];
  const float* b = (const float*)d_in[4];
  float* out = (float*)d_out;

  const int N = in_sizes[0] / D;
  const int E = in_sizes[2];
  const int NB = (N + 255) / 256;
  const int nr = (N + RNG - 1) / RNG;

  char* ws = (char*)d_ws;
  size_t off = 0;
  auto alloc = [&](size_t bytes) {
    char* p = ws + off;
    off = (off + bytes + 255) & ~(size_t)255;
    return p;
  };
  float* Wt = (float*)alloc((size_t)D * D * 4);
  uint2* yb = (uint2*)alloc((size_t)N * D * 2);  // bf16 y
  float* dinv = (float*)alloc((size_t)N * 4);
  float* pdeg = (float*)alloc((size_t)nr * HCHUNKS * RNG * 4);
  unsigned short* pcnt =
      (unsigned short*)alloc((size_t)nr * HCHUNKS * RNG * 2);
  int* cbase = (int*)alloc((size_t)HCHUNKS * N * 4);
  int* rowptr = (int*)alloc((size_t)(N + 1) * 4);
  int* blocksum = (int*)alloc((size_t)NB * 4);
  int* blockoff = (int*)alloc((size_t)NB * 4);
  int2* edges = (int2*)alloc((size_t)E * 8);
  int* flag = (int*)alloc(4);

  hipLaunchKernelGGL(k_setup, dim3((D * D + 255) / 256), dim3(256), 0, stream,
                     W, ei, Wt, flag);
  hipLaunchKernelGGL(k_gemm, dim3((N + GROWS - 1) / GROWS), dim3(256), 0,
                     stream, x, Wt, yb, N);
  hipLaunchKernelGGL(k_hist, dim3(HCHUNKS, nr), dim3(256), 0, stream,
                     ei, ew, pdeg, pcnt, flag, E);
  hipLaunchKernelGGL(k_scan1, dim3(NB), dim3(256), 0, stream,
                     pdeg, pcnt, dinv, rowptr, blocksum, N);
  hipLaunchKernelGGL(k_scan2, dim3(1), dim3(64), 0, stream,
                     blocksum, blockoff, NB);
  hipLaunchKernelGGL(k_scan3base, dim3(NB + 1), dim3(256), 0, stream,
                     rowptr, blockoff, pcnt, cbase, N, E);
  hipLaunchKernelGGL(k_scatter, dim3(HCHUNKS, nr), dim3(256), 0, stream,
                     ei, ew, dinv, cbase, edges, flag, N, E);
  hipLaunchKernelGGL(k_gather, dim3((N + 3) / 4), dim3(256), 0, stream,
                     rowptr, edges, yb, dinv, b, out, N);
}

// Round 8
// 199.676 us; speedup vs baseline: 1.1508x; 1.1169x over previous
//
#include <hip/hip_runtime.h>

#define D 128
#define HCHUNKS 128  // edge chunks (epc = 4688 < 2^16 -> u16 counts)
#define RNG 8064     // nodes per range: hist LDS f32+i32 = 63KB, scatter 32KB

typedef __attribute__((ext_vector_type(8))) short bf16x8;
typedef __attribute__((ext_vector_type(4))) float f32x4;

// ---------------------------------------------------------------------------
// GCN: out = A_norm @ (x @ W^T) + b.
// R1: per-edge f32 atomics write through HBM (300MB) -> CSR gather.
// R2: 2-atomics/edge build = 37MB atomic sectors ~58us.
// R3: fusing GEMM with global-atomic pass stacked, didn't overlap.
// R4: bucket LDS-tile agg regressed (serial shfl loop). 537us.
// R5: 1-atomic rank + LDS-hist degree + bf16 y. 228us.
// R6: atomic-free build; scatter 44us @8% occupancy. 229us.
// R7: scatter RNG=8064/HCHUNKS=128 -> all kernels < fill(44us). 223us.
// R8: MFMA bf16 GEMM (fp32 vector GEMM was ~32us FMA-bound); scan2 folded
//     into scan3base; gather uses cbase[0] as rowptr.
// ---------------------------------------------------------------------------

__device__ __forceinline__ unsigned bf16rne(float f) {
  unsigned u = __float_as_uint(f);
  return (u + 0x7FFFu + ((u >> 16) & 1u)) >> 16;
}

__device__ __forceinline__ float4 bf16x4u(uint2 u) {
  float4 r;
  r.x = __uint_as_float(u.x << 16);
  r.y = __uint_as_float(u.x & 0xFFFF0000u);
  r.z = __uint_as_float(u.y << 16);
  r.w = __uint_as_float(u.y & 0xFFFF0000u);
  return r;
}

// Pack W into MFMA B-fragment order, bf16:
// Wtb[((n0*4+k0)*64+lane)*8 + j] = W[n0*16+(lane&15)][k0*32+(lane>>4)*8+j]
__global__ __launch_bounds__(256) void k_setup(const float* __restrict__ W,
                                               const int* __restrict__ ei,
                                               unsigned short* __restrict__ Wtb,
                                               int* __restrict__ flag) {
  int t = blockIdx.x * 256 + threadIdx.x;  // 0..2047
  int lane = t & 63;
  int k0 = (t >> 6) & 3;
  int n0 = t >> 8;
  int n = n0 * 16 + (lane & 15);
  int kb = k0 * 32 + ((lane >> 4) << 3);
  const float4* wr = reinterpret_cast<const float4*>(W + n * D + kb);
  float4 a = wr[0], c = wr[1];
  unsigned short* dst = Wtb + (size_t)t * 8;
  dst[0] = bf16rne(a.x); dst[1] = bf16rne(a.y);
  dst[2] = bf16rne(a.z); dst[3] = bf16rne(a.w);
  dst[4] = bf16rne(c.x); dst[5] = bf16rne(c.y);
  dst[6] = bf16rne(c.z); dst[7] = bf16rne(c.w);
  if (t == 0) {
    // int64-vs-int32 edge_index layout: ids < 2^31 so int64(LE) odd dwords==0
    flag[0] = (ei[1] == 0 && ei[3] == 0 && ei[5] == 0 && ei[7] == 0) ? 1 : 0;
  }
}

// y = x @ W^T via mfma_f32_16x16x32_bf16. Block = 64 rows; 4 waves, one
// 16-row group each. x staged fp32->bf16 into LDS in A-frag order.
__global__ __launch_bounds__(256) void k_gemm(const float* __restrict__ x,
                                              const unsigned short* __restrict__ Wtb,
                                              unsigned short* __restrict__ ybs,
                                              int N) {
  __shared__ unsigned short XA[4 * 4 * 64 * 8];  // 16 KB
  __shared__ unsigned short WB[8 * 4 * 64 * 8];  // 32 KB
  const int tid = threadIdx.x;
  const int row0 = blockIdx.x * 64;

  // stage W frags (straight 32KB copy, coalesced)
  {
    const uint4* src = reinterpret_cast<const uint4*>(Wtb);
    uint4* dst = reinterpret_cast<uint4*>(WB);
#pragma unroll
    for (int k = 0; k < 8; ++k) dst[tid + k * 256] = src[tid + k * 256];
  }
  // stage x tile -> bf16 A-frag order
  for (int idx = tid; idx < 64 * 32; idx += 256) {
    int row = idx >> 5;          // 0..63
    int c4 = (idx & 31) * 4;     // 0..124
    float4 v = make_float4(0.f, 0.f, 0.f, 0.f);
    int grow = row0 + row;
    if (grow < N)
      v = reinterpret_cast<const float4*>(x)[((size_t)grow * D + c4) >> 2];
    int g = row >> 4, mr = row & 15;
    int k0 = c4 >> 5, quad = (c4 >> 3) & 3, j = c4 & 7;
    unsigned short* p =
        &XA[(((g * 4 + k0) * 64) + quad * 16 + mr) * 8 + j];
    p[0] = bf16rne(v.x); p[1] = bf16rne(v.y);
    p[2] = bf16rne(v.z); p[3] = bf16rne(v.w);
  }
  __syncthreads();

  const int g = tid >> 6, lane = tid & 63;
  bf16x8 a[4];
#pragma unroll
  for (int k0 = 0; k0 < 4; ++k0)
    a[k0] = *reinterpret_cast<const bf16x8*>(&XA[((g * 4 + k0) * 64 + lane) * 8]);

  const int colb = lane & 15;
  const int rbase = row0 + g * 16 + ((lane >> 4) << 2);
#pragma unroll
  for (int n0 = 0; n0 < 8; ++n0) {
    f32x4 acc = {0.f, 0.f, 0.f, 0.f};
#pragma unroll
    for (int k0 = 0; k0 < 4; ++k0) {
      bf16x8 bfr =
          *reinterpret_cast<const bf16x8*>(&WB[((n0 * 4 + k0) * 64 + lane) * 8]);
      acc = __builtin_amdgcn_mfma_f32_16x16x32_bf16(a[k0], bfr, acc, 0, 0, 0);
    }
    int col = n0 * 16 + colb;
#pragma unroll
    for (int reg = 0; reg < 4; ++reg) {
      int row = rbase + reg;
      if (row < N) ybs[(size_t)row * D + col] = (unsigned short)bf16rne(acc[reg]);
    }
  }
}

// chunked private histograms: deg (f32 over src) + cnt (i32 over tgt, stored
// u16). grid (HCHUNKS, nranges). No global atomics.
__global__ __launch_bounds__(256) void k_hist(const int* __restrict__ ei,
                                              const float* __restrict__ ew,
                                              float* __restrict__ pdeg,
                                              unsigned short* __restrict__ pcnt,
                                              const int* __restrict__ flag,
                                              int E) {
  __shared__ float hd[RNG];
  __shared__ int hc[RNG];
  const int tid = threadIdx.x;
  const int chunk = blockIdx.x, r = blockIdx.y;
  const int lo = r * RNG;
  for (int i = tid; i < RNG; i += 256) { hd[i] = 0.f; hc[i] = 0; }
  __syncthreads();

  const int epc = (E + HCHUNKS - 1) / HCHUNKS;
  const int e0 = chunk * epc;
  const int e1 = min(e0 + epc, E);
  const bool f64 = flag[0] != 0;
  const int2* ei2 = reinterpret_cast<const int2*>(ei);
  for (int e = e0 + tid; e < e1; e += 256) {
    int s = f64 ? ei2[e].x : ei[e];
    int t = f64 ? ei2[E + e].x : ei[E + e];
    int ds = s - lo;
    if ((unsigned)ds < (unsigned)RNG) atomicAdd(&hd[ds], ew[e]);
    int dt = t - lo;
    if ((unsigned)dt < (unsigned)RNG) atomicAdd(&hc[dt], 1);
  }
  __syncthreads();
  size_t base = ((size_t)r * HCHUNKS + chunk) * RNG;
  for (int i = tid; i < RNG; i += 256) {
    pdeg[base + i] = hd[i];
    pcnt[base + i] = (unsigned short)hc[i];
  }
}

__device__ __forceinline__ int wave_incl_scan(int v, int lane) {
#pragma unroll
  for (int o = 1; o < 64; o <<= 1) {
    int t = __shfl_up(v, o);
    if (lane >= o) v += t;
  }
  return v;
}

// fused: reduce pdeg -> dinv, reduce pcnt -> v, block-exclusive-scan v
__global__ __launch_bounds__(256) void k_scan1(const float* __restrict__ pdeg,
                                               const unsigned short* __restrict__ pcnt,
                                               float* __restrict__ dinv,
                                               int* __restrict__ rowptr,
                                               int* __restrict__ blocksum,
                                               int N) {
  __shared__ int wtot[4];
  int tid = threadIdx.x;
  int i = blockIdx.x * 256 + tid;
  int v = 0;
  if (i < N) {
    int r = i / RNG, off = i - r * RNG;
    size_t base = (size_t)r * HCHUNKS * RNG + off;
    float s = 0.f;
    int c = 0;
#pragma unroll 8
    for (int k = 0; k < HCHUNKS; ++k) {
      s += pdeg[base + (size_t)k * RNG];
      c += pcnt[base + (size_t)k * RNG];
    }
    dinv[i] = rsqrtf(s + 1.0f);  // +1 = self-loop weight
    v = c;
  }
  int lane = tid & 63, wv = tid >> 6;
  int inc = wave_incl_scan(v, lane);
  if (lane == 63) wtot[wv] = inc;
  __syncthreads();
  if (tid == 0) {
    int r = 0;
#pragma unroll
    for (int k = 0; k < 4; ++k) { int t = wtot[k]; wtot[k] = r; r += t; }
  }
  __syncthreads();
  int exc = wtot[wv] + inc - v;
  if (i < N) rowptr[i] = exc;
  if (tid == 255) blocksum[blockIdx.x] = wtot[3] + inc;
}

// inline block-offset scan (replaces k_scan2) + per-chunk cursor emit:
// cbase[c*N+v] = rowptr_final[v] + prefix_c(cnt). cbase[0][.] IS final rowptr.
__global__ __launch_bounds__(256) void k_scan3base(const int* __restrict__ rowptr,
                                                   const int* __restrict__ blocksum,
                                                   const unsigned short* __restrict__ pcnt,
                                                   int* __restrict__ cbase,
                                                   int N) {
  __shared__ int sboff;
  const int tid = threadIdx.x;
  const int bid = blockIdx.x;
  if (tid < 64) {
    int s = 0;
    for (int k = tid; k < bid; k += 64) s += blocksum[k];
#pragma unroll
    for (int o = 1; o < 64; o <<= 1) s += __shfl_xor(s, o);
    if (tid == 0) sboff = s;
  }
  __syncthreads();
  int i = bid * 256 + tid;
  if (i >= N) return;
  int run = rowptr[i] + sboff;
  int r = i / RNG, off = i - r * RNG;
  size_t pb = (size_t)r * HCHUNKS * RNG + off;
#pragma unroll 8
  for (int c = 0; c < HCHUNKS; ++c) {
    cbase[(size_t)c * N + i] = run;
    run += pcnt[pb + (size_t)c * RNG];
  }
}

// scatter: LDS cursor bump gives final CSR slot; plain 8B stores.
__global__ __launch_bounds__(256) void k_scatter(const int* __restrict__ ei,
                                                 const float* __restrict__ ew,
                                                 const float* __restrict__ dinv,
                                                 const int* __restrict__ cbase,
                                                 int2* __restrict__ edges,
                                                 const int* __restrict__ flag,
                                                 int N, int E) {
  __shared__ int hb[RNG];
  const int tid = threadIdx.x;
  const int chunk = blockIdx.x, r = blockIdx.y;
  const int lo = r * RNG;
  for (int j = tid; j < RNG; j += 256) {
    int v = lo + j;
    hb[j] = (v < N) ? cbase[(size_t)chunk * N + v] : 0;
  }
  __syncthreads();

  const int epc = (E + HCHUNKS - 1) / HCHUNKS;
  const int e0 = chunk * epc;
  const int e1 = min(e0 + epc, E);
  const bool f64 = flag[0] != 0;
  const int2* ei2 = reinterpret_cast<const int2*>(ei);
  for (int e = e0 + tid; e < e1; e += 256) {
    int t = f64 ? ei2[E + e].x : ei[E + e];
    int dt = t - lo;
    if ((unsigned)dt < (unsigned)RNG) {
      int s = f64 ? ei2[e].x : ei[e];
      int pos = atomicAdd(&hb[dt], 1);  // LDS atomic -> final global slot
      edges[pos] = make_int2(s, __float_as_int(ew[e] * dinv[s]));
    }
  }
}

// gather: node per wave; 32-lane halves, 4 bf16/lane, 8 rows in flight.
// rowptr == cbase[0]; out = b + dt*(sum_e wn*y[s] + dt*y[node])
__global__ __launch_bounds__(256) void k_gather(const int* __restrict__ rp0,
                                                const int2* __restrict__ edges,
                                                const uint2* __restrict__ yb,
                                                const float* __restrict__ dinv,
                                                const float* __restrict__ b,
                                                float* __restrict__ out,
                                                int N, int E) {
  const int tid = threadIdx.x;
  const int node = blockIdx.x * 4 + (tid >> 6);
  if (node >= N) return;
  const int lane = tid & 63, half = lane >> 5, l32 = lane & 31;

  const float dt = dinv[node];
  const float4 yself = bf16x4u(yb[(size_t)node * 32 + l32]);
  const float4 bb = reinterpret_cast<const float4*>(b)[l32];

  float4 acc = make_float4(0.f, 0.f, 0.f, 0.f);
  const int end = (node + 1 < N) ? rp0[node + 1] : E;
  int e = rp0[node] + half;
  for (; e + 6 < end; e += 8) {  // 4 rows in flight per half
    int2 e0 = edges[e], e1 = edges[e + 2], e2 = edges[e + 4], e3 = edges[e + 6];
    float4 v0 = bf16x4u(yb[(size_t)e0.x * 32 + l32]);
    float4 v1 = bf16x4u(yb[(size_t)e1.x * 32 + l32]);
    float4 v2 = bf16x4u(yb[(size_t)e2.x * 32 + l32]);
    float4 v3 = bf16x4u(yb[(size_t)e3.x * 32 + l32]);
    float w0 = __int_as_float(e0.y), w1 = __int_as_float(e1.y);
    float w2 = __int_as_float(e2.y), w3 = __int_as_float(e3.y);
    acc.x += w0 * v0.x; acc.y += w0 * v0.y; acc.z += w0 * v0.z; acc.w += w0 * v0.w;
    acc.x += w1 * v1.x; acc.y += w1 * v1.y; acc.z += w1 * v1.z; acc.w += w1 * v1.w;
    acc.x += w2 * v2.x; acc.y += w2 * v2.y; acc.z += w2 * v2.z; acc.w += w2 * v2.w;
    acc.x += w3 * v3.x; acc.y += w3 * v3.y; acc.z += w3 * v3.z; acc.w += w3 * v3.w;
  }
  for (; e < end; e += 2) {
    int2 e0 = edges[e];
    float4 v0 = bf16x4u(yb[(size_t)e0.x * 32 + l32]);
    float w0 = __int_as_float(e0.y);
    acc.x += w0 * v0.x; acc.y += w0 * v0.y; acc.z += w0 * v0.z; acc.w += w0 * v0.w;
  }
  acc.x += __shfl(acc.x, l32 + 32);
  acc.y += __shfl(acc.y, l32 + 32);
  acc.z += __shfl(acc.z, l32 + 32);
  acc.w += __shfl(acc.w, l32 + 32);
  if (half == 0) {
    float4 r;
    r.x = bb.x + dt * (acc.x + dt * yself.x);
    r.y = bb.y + dt * (acc.y + dt * yself.y);
    r.z = bb.z + dt * (acc.z + dt * yself.z);
    r.w = bb.w + dt * (acc.w + dt * yself.w);
    reinterpret_cast<float4*>(out)[(size_t)node * 32 + l32] = r;
  }
}

extern "C" void kernel_launch(void* const* d_in, const int* in_sizes, int n_in,
                              void* d_out, int out_size, void* d_ws, size_t ws_size,
                              hipStream_t stream) {
  const float* x = (const float*)d_in[0];
  const int* ei = (const int*)d_in[1];
  const float* ew = (const float*)d_in[2];
  const float* W = (const float*)d_in[3];
  const float* b = (const float*)d_in[4];
  float* out = (float*)d_out;

  const int N = in_sizes[0] / D;
  const int E = in_sizes[2];
  const int NB = (N + 255) / 256;
  const int nr = (N + RNG - 1) / RNG;

  char* ws = (char*)d_ws;
  size_t off = 0;
  auto alloc = [&](size_t bytes) {
    char* p = ws + off;
    off = (off + bytes + 255) & ~(size_t)255;
    return p;
  };
  unsigned short* Wtb = (unsigned short*)alloc((size_t)D * D * 2);  // frag bf16
  uint2* yb = (uint2*)alloc((size_t)N * D * 2);  // bf16 y
  float* dinv = (float*)alloc((size_t)N * 4);
  float* pdeg = (float*)alloc((size_t)nr * HCHUNKS * RNG * 4);
  unsigned short* pcnt =
      (unsigned short*)alloc((size_t)nr * HCHUNKS * RNG * 2);
  int* cbase = (int*)alloc((size_t)HCHUNKS * N * 4);
  int* rowptr = (int*)alloc((size_t)N * 4);
  int* blocksum = (int*)alloc((size_t)NB * 4);
  int2* edges = (int2*)alloc((size_t)E * 8);
  int* flag = (int*)alloc(4);

  hipLaunchKernelGGL(k_setup, dim3(8), dim3(256), 0, stream, W, ei, Wtb, flag);
  hipLaunchKernelGGL(k_gemm, dim3((N + 63) / 64), dim3(256), 0, stream,
                     x, Wtb, (unsigned short*)yb, N);
  hipLaunchKernelGGL(k_hist, dim3(HCHUNKS, nr), dim3(256), 0, stream,
                     ei, ew, pdeg, pcnt, flag, E);
  hipLaunchKernelGGL(k_scan1, dim3(NB), dim3(256), 0, stream,
                     pdeg, pcnt, dinv, rowptr, blocksum, N);
  hipLaunchKernelGGL(k_scan3base, dim3(NB), dim3(256), 0, stream,
                     rowptr, blocksum, pcnt, cbase, N);
  hipLaunchKernelGGL(k_scatter, dim3(HCHUNKS, nr), dim3(256), 0, stream,
                     ei, ew, dinv, cbase, edges, flag, N, E);
  hipLaunchKernelGGL(k_gather, dim3((N + 3) / 4), dim3(256), 0, stream,
                     cbase, edges, yb, dinv, b, out, N, E);
}

// Round 10
// 196.619 us; speedup vs baseline: 1.1687x; 1.0155x over previous
//
#include <hip/hip_runtime.h>

#define D 128
#define HCHUNKS 64   // edge chunks (epc = 9375 < 2^16 -> u16 counts)
#define RNG 8064     // nodes per range: hist LDS f32+i32 = 63KB, scatter 32KB

typedef __attribute__((ext_vector_type(8))) short bf16x8;
typedef __attribute__((ext_vector_type(4))) float f32x4;

// ---------------------------------------------------------------------------
// GCN: out = A_norm @ (x @ W^T) + b.
// R1: per-edge f32 atomics write through HBM (300MB) -> CSR gather.
// R2: 2-atomics/edge build = 37MB atomic sectors ~58us.
// R3: fusing GEMM with global-atomic pass stacked, didn't overlap.
// R4: bucket LDS-tile agg regressed (serial shfl loop). 537us.
// R5: 1-atomic rank + LDS-hist degree + bf16 y. 228us.
// R6: atomic-free build; scatter 44us @8% occupancy. 229us.
// R7: scatter RNG=8064/HCHUNKS=128. 223us.
// R8: MFMA bf16 GEMM; scan2 folded into scan3base. 199.7us (PASS).
// R9: HCHUNKS=64 + k_setup removed (per-block ei flag, in-gemm W pack):
//     FAILED post-timing revalidation (absmax 1.46) despite passing the
//     fresh-launch check. Could not root-cause by inspection.
// R10: bisect — exact R8 code, ONLY HCHUNKS 128->64 (halves pdeg/pcnt/cbase
//     traffic). k_setup/flag/Wtb restored verbatim from the passing R8.
// ---------------------------------------------------------------------------

__device__ __forceinline__ unsigned bf16rne(float f) {
  unsigned u = __float_as_uint(f);
  return (u + 0x7FFFu + ((u >> 16) & 1u)) >> 16;
}

__device__ __forceinline__ float4 bf16x4u(uint2 u) {
  float4 r;
  r.x = __uint_as_float(u.x << 16);
  r.y = __uint_as_float(u.x & 0xFFFF0000u);
  r.z = __uint_as_float(u.y << 16);
  r.w = __uint_as_float(u.y & 0xFFFF0000u);
  return r;
}

// Pack W into MFMA B-fragment order, bf16:
// Wtb[((n0*4+k0)*64+lane)*8 + j] = W[n0*16+(lane&15)][k0*32+(lane>>4)*8+j]
__global__ __launch_bounds__(256) void k_setup(const float* __restrict__ W,
                                               const int* __restrict__ ei,
                                               unsigned short* __restrict__ Wtb,
                                               int* __restrict__ flag) {
  int t = blockIdx.x * 256 + threadIdx.x;  // 0..2047
  int lane = t & 63;
  int k0 = (t >> 6) & 3;
  int n0 = t >> 8;
  int n = n0 * 16 + (lane & 15);
  int kb = k0 * 32 + ((lane >> 4) << 3);
  const float4* wr = reinterpret_cast<const float4*>(W + n * D + kb);
  float4 a = wr[0], c = wr[1];
  unsigned short* dst = Wtb + (size_t)t * 8;
  dst[0] = bf16rne(a.x); dst[1] = bf16rne(a.y);
  dst[2] = bf16rne(a.z); dst[3] = bf16rne(a.w);
  dst[4] = bf16rne(c.x); dst[5] = bf16rne(c.y);
  dst[6] = bf16rne(c.z); dst[7] = bf16rne(c.w);
  if (t == 0) {
    // int64-vs-int32 edge_index layout: ids < 2^31 so int64(LE) odd dwords==0
    flag[0] = (ei[1] == 0 && ei[3] == 0 && ei[5] == 0 && ei[7] == 0) ? 1 : 0;
  }
}

// y = x @ W^T via mfma_f32_16x16x32_bf16. Block = 64 rows; 4 waves, one
// 16-row group each. x staged fp32->bf16 into LDS in A-frag order.
__global__ __launch_bounds__(256) void k_gemm(const float* __restrict__ x,
                                              const unsigned short* __restrict__ Wtb,
                                              unsigned short* __restrict__ ybs,
                                              int N) {
  __shared__ unsigned short XA[4 * 4 * 64 * 8];  // 16 KB
  __shared__ unsigned short WB[8 * 4 * 64 * 8];  // 32 KB
  const int tid = threadIdx.x;
  const int row0 = blockIdx.x * 64;

  // stage W frags (straight 32KB copy, coalesced)
  {
    const uint4* src = reinterpret_cast<const uint4*>(Wtb);
    uint4* dst = reinterpret_cast<uint4*>(WB);
#pragma unroll
    for (int k = 0; k < 8; ++k) dst[tid + k * 256] = src[tid + k * 256];
  }
  // stage x tile -> bf16 A-frag order
  for (int idx = tid; idx < 64 * 32; idx += 256) {
    int row = idx >> 5;          // 0..63
    int c4 = (idx & 31) * 4;     // 0..124
    float4 v = make_float4(0.f, 0.f, 0.f, 0.f);
    int grow = row0 + row;
    if (grow < N)
      v = reinterpret_cast<const float4*>(x)[((size_t)grow * D + c4) >> 2];
    int g = row >> 4, mr = row & 15;
    int k0 = c4 >> 5, quad = (c4 >> 3) & 3, j = c4 & 7;
    unsigned short* p =
        &XA[(((g * 4 + k0) * 64) + quad * 16 + mr) * 8 + j];
    p[0] = bf16rne(v.x); p[1] = bf16rne(v.y);
    p[2] = bf16rne(v.z); p[3] = bf16rne(v.w);
  }
  __syncthreads();

  const int g = tid >> 6, lane = tid & 63;
  bf16x8 a[4];
#pragma unroll
  for (int k0 = 0; k0 < 4; ++k0)
    a[k0] = *reinterpret_cast<const bf16x8*>(&XA[((g * 4 + k0) * 64 + lane) * 8]);

  const int colb = lane & 15;
  const int rbase = row0 + g * 16 + ((lane >> 4) << 2);
#pragma unroll
  for (int n0 = 0; n0 < 8; ++n0) {
    f32x4 acc = {0.f, 0.f, 0.f, 0.f};
#pragma unroll
    for (int k0 = 0; k0 < 4; ++k0) {
      bf16x8 bfr =
          *reinterpret_cast<const bf16x8*>(&WB[((n0 * 4 + k0) * 64 + lane) * 8]);
      acc = __builtin_amdgcn_mfma_f32_16x16x32_bf16(a[k0], bfr, acc, 0, 0, 0);
    }
    int col = n0 * 16 + colb;
#pragma unroll
    for (int reg = 0; reg < 4; ++reg) {
      int row = rbase + reg;
      if (row < N) ybs[(size_t)row * D + col] = (unsigned short)bf16rne(acc[reg]);
    }
  }
}

// chunked private histograms: deg (f32 over src) + cnt (i32 over tgt, stored
// u16). grid (HCHUNKS, nranges). No global atomics.
__global__ __launch_bounds__(256) void k_hist(const int* __restrict__ ei,
                                              const float* __restrict__ ew,
                                              float* __restrict__ pdeg,
                                              unsigned short* __restrict__ pcnt,
                                              const int* __restrict__ flag,
                                              int E) {
  __shared__ float hd[RNG];
  __shared__ int hc[RNG];
  const int tid = threadIdx.x;
  const int chunk = blockIdx.x, r = blockIdx.y;
  const int lo = r * RNG;
  for (int i = tid; i < RNG; i += 256) { hd[i] = 0.f; hc[i] = 0; }
  __syncthreads();

  const int epc = (E + HCHUNKS - 1) / HCHUNKS;
  const int e0 = chunk * epc;
  const int e1 = min(e0 + epc, E);
  const bool f64 = flag[0] != 0;
  const int2* ei2 = reinterpret_cast<const int2*>(ei);
  for (int e = e0 + tid; e < e1; e += 256) {
    int s = f64 ? ei2[e].x : ei[e];
    int t = f64 ? ei2[E + e].x : ei[E + e];
    int ds = s - lo;
    if ((unsigned)ds < (unsigned)RNG) atomicAdd(&hd[ds], ew[e]);
    int dt = t - lo;
    if ((unsigned)dt < (unsigned)RNG) atomicAdd(&hc[dt], 1);
  }
  __syncthreads();
  size_t base = ((size_t)r * HCHUNKS + chunk) * RNG;
  for (int i = tid; i < RNG; i += 256) {
    pdeg[base + i] = hd[i];
    pcnt[base + i] = (unsigned short)hc[i];
  }
}

__device__ __forceinline__ int wave_incl_scan(int v, int lane) {
#pragma unroll
  for (int o = 1; o < 64; o <<= 1) {
    int t = __shfl_up(v, o);
    if (lane >= o) v += t;
  }
  return v;
}

// fused: reduce pdeg -> dinv, reduce pcnt -> v, block-exclusive-scan v
__global__ __launch_bounds__(256) void k_scan1(const float* __restrict__ pdeg,
                                               const unsigned short* __restrict__ pcnt,
                                               float* __restrict__ dinv,
                                               int* __restrict__ rowptr,
                                               int* __restrict__ blocksum,
                                               int N) {
  __shared__ int wtot[4];
  int tid = threadIdx.x;
  int i = blockIdx.x * 256 + tid;
  int v = 0;
  if (i < N) {
    int r = i / RNG, off = i - r * RNG;
    size_t base = (size_t)r * HCHUNKS * RNG + off;
    float s = 0.f;
    int c = 0;
#pragma unroll 8
    for (int k = 0; k < HCHUNKS; ++k) {
      s += pdeg[base + (size_t)k * RNG];
      c += pcnt[base + (size_t)k * RNG];
    }
    dinv[i] = rsqrtf(s + 1.0f);  // +1 = self-loop weight
    v = c;
  }
  int lane = tid & 63, wv = tid >> 6;
  int inc = wave_incl_scan(v, lane);
  if (lane == 63) wtot[wv] = inc;
  __syncthreads();
  if (tid == 0) {
    int r = 0;
#pragma unroll
    for (int k = 0; k < 4; ++k) { int t = wtot[k]; wtot[k] = r; r += t; }
  }
  __syncthreads();
  int exc = wtot[wv] + inc - v;
  if (i < N) rowptr[i] = exc;
  if (tid == 255) blocksum[blockIdx.x] = wtot[3] + inc;
}

// inline block-offset scan (replaces k_scan2) + per-chunk cursor emit:
// cbase[c*N+v] = rowptr_final[v] + prefix_c(cnt). cbase[0][.] IS final rowptr.
__global__ __launch_bounds__(256) void k_scan3base(const int* __restrict__ rowptr,
                                                   const int* __restrict__ blocksum,
                                                   const unsigned short* __restrict__ pcnt,
                                                   int* __restrict__ cbase,
                                                   int N) {
  __shared__ int sboff;
  const int tid = threadIdx.x;
  const int bid = blockIdx.x;
  if (tid < 64) {
    int s = 0;
    for (int k = tid; k < bid; k += 64) s += blocksum[k];
#pragma unroll
    for (int o = 1; o < 64; o <<= 1) s += __shfl_xor(s, o);
    if (tid == 0) sboff = s;
  }
  __syncthreads();
  int i = bid * 256 + tid;
  if (i >= N) return;
  int run = rowptr[i] + sboff;
  int r = i / RNG, off = i - r * RNG;
  size_t pb = (size_t)r * HCHUNKS * RNG + off;
#pragma unroll 8
  for (int c = 0; c < HCHUNKS; ++c) {
    cbase[(size_t)c * N + i] = run;
    run += pcnt[pb + (size_t)c * RNG];
  }
}

// scatter: LDS cursor bump gives final CSR slot; plain 8B stores.
__global__ __launch_bounds__(256) void k_scatter(const int* __restrict__ ei,
                                                 const float* __restrict__ ew,
                                                 const float* __restrict__ dinv,
                                                 const int* __restrict__ cbase,
                                                 int2* __restrict__ edges,
                                                 const int* __restrict__ flag,
                                                 int N, int E) {
  __shared__ int hb[RNG];
  const int tid = threadIdx.x;
  const int chunk = blockIdx.x, r = blockIdx.y;
  const int lo = r * RNG;
  for (int j = tid; j < RNG; j += 256) {
    int v = lo + j;
    hb[j] = (v < N) ? cbase[(size_t)chunk * N + v] : 0;
  }
  __syncthreads();

  const int epc = (E + HCHUNKS - 1) / HCHUNKS;
  const int e0 = chunk * epc;
  const int e1 = min(e0 + epc, E);
  const bool f64 = flag[0] != 0;
  const int2* ei2 = reinterpret_cast<const int2*>(ei);
  for (int e = e0 + tid; e < e1; e += 256) {
    int t = f64 ? ei2[E + e].x : ei[E + e];
    int dt = t - lo;
    if ((unsigned)dt < (unsigned)RNG) {
      int s = f64 ? ei2[e].x : ei[e];
      int pos = atomicAdd(&hb[dt], 1);  // LDS atomic -> final global slot
      edges[pos] = make_int2(s, __float_as_int(ew[e] * dinv[s]));
    }
  }
}

// gather: node per wave; 32-lane halves, 4 bf16/lane, 8 rows in flight.
// rowptr == cbase[0]; out = b + dt*(sum_e wn*y[s] + dt*y[node])
__global__ __launch_bounds__(256) void k_gather(const int* __restrict__ rp0,
                                                const int2* __restrict__ edges,
                                                const uint2* __restrict__ yb,
                                                const float* __restrict__ dinv,
                                                const float* __restrict__ b,
                                                float* __restrict__ out,
                                                int N, int E) {
  const int tid = threadIdx.x;
  const int node = blockIdx.x * 4 + (tid >> 6);
  if (node >= N) return;
  const int lane = tid & 63, half = lane >> 5, l32 = lane & 31;

  const float dt = dinv[node];
  const float4 yself = bf16x4u(yb[(size_t)node * 32 + l32]);
  const float4 bb = reinterpret_cast<const float4*>(b)[l32];

  float4 acc = make_float4(0.f, 0.f, 0.f, 0.f);
  const int end = (node + 1 < N) ? rp0[node + 1] : E;
  int e = rp0[node] + half;
  for (; e + 6 < end; e += 8) {  // 4 rows in flight per half
    int2 e0 = edges[e], e1 = edges[e + 2], e2 = edges[e + 4], e3 = edges[e + 6];
    float4 v0 = bf16x4u(yb[(size_t)e0.x * 32 + l32]);
    float4 v1 = bf16x4u(yb[(size_t)e1.x * 32 + l32]);
    float4 v2 = bf16x4u(yb[(size_t)e2.x * 32 + l32]);
    float4 v3 = bf16x4u(yb[(size_t)e3.x * 32 + l32]);
    float w0 = __int_as_float(e0.y), w1 = __int_as_float(e1.y);
    float w2 = __int_as_float(e2.y), w3 = __int_as_float(e3.y);
    acc.x += w0 * v0.x; acc.y += w0 * v0.y; acc.z += w0 * v0.z; acc.w += w0 * v0.w;
    acc.x += w1 * v1.x; acc.y += w1 * v1.y; acc.z += w1 * v1.z; acc.w += w1 * v1.w;
    acc.x += w2 * v2.x; acc.y += w2 * v2.y; acc.z += w2 * v2.z; acc.w += w2 * v2.w;
    acc.x += w3 * v3.x; acc.y += w3 * v3.y; acc.z += w3 * v3.z; acc.w += w3 * v3.w;
  }
  for (; e < end; e += 2) {
    int2 e0 = edges[e];
    float4 v0 = bf16x4u(yb[(size_t)e0.x * 32 + l32]);
    float w0 = __int_as_float(e0.y);
    acc.x += w0 * v0.x; acc.y += w0 * v0.y; acc.z += w0 * v0.z; acc.w += w0 * v0.w;
  }
  acc.x += __shfl(acc.x, l32 + 32);
  acc.y += __shfl(acc.y, l32 + 32);
  acc.z += __shfl(acc.z, l32 + 32);
  acc.w += __shfl(acc.w, l32 + 32);
  if (half == 0) {
    float4 r;
    r.x = bb.x + dt * (acc.x + dt * yself.x);
    r.y = bb.y + dt * (acc.y + dt * yself.y);
    r.z = bb.z + dt * (acc.z + dt * yself.z);
    r.w = bb.w + dt * (acc.w + dt * yself.w);
    reinterpret_cast<float4*>(out)[(size_t)node * 32 + l32] = r;
  }
}

extern "C" void kernel_launch(void* const* d_in, const int* in_sizes, int n_in,
                              void* d_out, int out_size, void* d_ws, size_t ws_size,
                              hipStream_t stream) {
  const float* x = (const float*)d_in[0];
  const int* ei = (const int*)d_in[1];
  const float* ew = (const float*)d_in[2];
  const float* W = (const float*)d_in[3];
  const float* b = (const float*)d_in[4];
  float* out = (float*)d_out;

  const int N = in_sizes[0] / D;
  const int E = in_sizes[2];
  const int NB = (N + 255) / 256;
  const int nr = (N + RNG - 1) / RNG;

  char* ws = (char*)d_ws;
  size_t off = 0;
  auto alloc = [&](size_t bytes) {
    char* p = ws + off;
    off = (off + bytes + 255) & ~(size_t)255;
    return p;
  };
  unsigned short* Wtb = (unsigned short*)alloc((size_t)D * D * 2);  // frag bf16
  uint2* yb = (uint2*)alloc((size_t)N * D * 2);  // bf16 y
  float* dinv = (float*)alloc((size_t)N * 4);
  float* pdeg = (float*)alloc((size_t)nr * HCHUNKS * RNG * 4);
  unsigned short* pcnt =
      (unsigned short*)alloc((size_t)nr * HCHUNKS * RNG * 2);
  int* cbase = (int*)alloc((size_t)HCHUNKS * N * 4);
  int* rowptr = (int*)alloc((size_t)N * 4);
  int* blocksum = (int*)alloc((size_t)NB * 4);
  int2* edges = (int2*)alloc((size_t)E * 8);
  int* flag = (int*)alloc(4);

  hipLaunchKernelGGL(k_setup, dim3(8), dim3(256), 0, stream, W, ei, Wtb, flag);
  hipLaunchKernelGGL(k_gemm, dim3((N + 63) / 64), dim3(256), 0, stream,
                     x, Wtb, (unsigned short*)yb, N);
  hipLaunchKernelGGL(k_hist, dim3(HCHUNKS, nr), dim3(256), 0, stream,
                     ei, ew, pdeg, pcnt, flag, E);
  hipLaunchKernelGGL(k_scan1, dim3(NB), dim3(256), 0, stream,
                     pdeg, pcnt, dinv, rowptr, blocksum, N);
  hipLaunchKernelGGL(k_scan3base, dim3(NB), dim3(256), 0, stream,
                     rowptr, blocksum, pcnt, cbase, N);
  hipLaunchKernelGGL(k_scatter, dim3(HCHUNKS, nr), dim3(256), 0, stream,
                     ei, ew, dinv, cbase, edges, flag, N, E);
  hipLaunchKernelGGL(k_gather, dim3((N + 3) / 4), dim3(256), 0, stream,
                     cbase, edges, yb, dinv, b, out, N, E);
}